// Round 1
// baseline (298.620 us; speedup 1.0000x reference)
//
#include <hip/hip_runtime.h>

// Sizes (fixed by the problem):
// B=16, K=64 -> N = 1024 images of 28x28; conv1: 1->32ch 12x12; conv2: 32->64ch 4x4
// FLAT=1024, HID=D=128, OUT=S=128, m=64.

// ---------------------------------------------------------------------------
// K0: combine coefficient tensors (coeffs[d][s][p], p=0..14) into the matrices
// used by the decomposition:
//   out[b,s,i,j] = PP + U[i] + V[j] + W + delta_ij*(D[i] + dconst)
// ---------------------------------------------------------------------------
__global__ void k_prep(const float* __restrict__ coeffs,
                       float* __restrict__ Ca,  float* __restrict__ Cdg, float* __restrict__ Cdr,
                       float* __restrict__ Cug, float* __restrict__ Cur,
                       float* __restrict__ Cvg, float* __restrict__ Cvr,
                       float* __restrict__ Cct, float* __restrict__ CcA,
                       float* __restrict__ Cwt, float* __restrict__ CwA) {
    int idx = blockIdx.x * 256 + threadIdx.x;      // idx = d*128 + s
    if (idx >= 128 * 128) return;
    int d = idx >> 7, s = idx & 127;
    const float* c = coeffs + idx * 15;
    const float im = 1.0f / 64.0f, im2 = 1.0f / 4096.0f;
    Ca[s * 128 + d] = c[9] + c[10];                // P + P^T   (s-major for k_main)
    Cdg[idx] = c[0];                               // delta * g_i
    Cdr[idx] = (c[2] + c[3]) * im;                 // delta * r_i/m (rows==cols, symmetric P)
    Cur[idx] = (c[5] + c[6]) * im;                 // row r_i/m
    Cug[idx] = c[11];                              // row g_i
    Cvr[idx] = (c[7] + c[8]) * im;                 // col r_j/m
    Cvg[idx] = c[12];                              // col g_j
    Cct[idx] = c[1] * im;                          // delta * t/m
    CcA[idx] = c[4] * im2;                         // delta * A/m^2
    Cwt[idx] = c[13] * im;                         // const t/m
    CwA[idx] = c[14] * im2;                        // const A/m^2
}

// Transpose fc_w (128,1024) -> fcwT (1024,128) for coalesced GEMM B-loads.
__global__ void k_fcwT(const float* __restrict__ fc_w, float* __restrict__ fcwT) {
    int idx = blockIdx.x * 256 + threadIdx.x;
    if (idx >= 128 * 1024) return;
    int s = idx >> 10, k = idx & 1023;
    fcwT[k * 128 + s] = fc_w[idx];
}

// ---------------------------------------------------------------------------
// K1: conv1  (1024,1,28,28) -> relu -> (1024,32,12,12), 5x5 stride 2 VALID
// One thread per output; idx = ((n*32+oc)*144 + pos) so writes are coalesced.
// ---------------------------------------------------------------------------
__global__ __launch_bounds__(256) void k_conv1(const float* __restrict__ x,
                                               const float* __restrict__ w1,
                                               const float* __restrict__ b1,
                                               float* __restrict__ y1) {
    int idx = blockIdx.x * 256 + threadIdx.x;      // < 1024*32*144
    int pos = idx % 144;
    int t   = idx / 144;
    int oc  = t & 31;
    int n   = t >> 5;
    if (n >= 1024) return;
    int oy = pos / 12, ox = pos % 12;
    const float* xin = x + n * 784 + (oy * 2) * 28 + ox * 2;
    const float* wp  = w1 + oc * 25;
    float acc = b1[oc];
#pragma unroll
    for (int ky = 0; ky < 5; ++ky)
#pragma unroll
        for (int kx = 0; kx < 5; ++kx)
            acc = fmaf(xin[ky * 28 + kx], wp[ky * 5 + kx], acc);
    y1[idx] = fmaxf(acc, 0.0f);
}

// ---------------------------------------------------------------------------
// K2: conv2  (1024,32,12,12) -> relu -> (1024,64,4,4)
// One block per image n; input (18 KiB) staged in LDS; thread = (oc, oy),
// 4 outputs (all ox) per thread; row of 12 held in registers.
// ---------------------------------------------------------------------------
__global__ __launch_bounds__(256) void k_conv2(const float* __restrict__ y1,
                                               const float* __restrict__ w2,
                                               const float* __restrict__ b2,
                                               float* __restrict__ y2) {
    __shared__ alignas(16) float in_s[32 * 144];
    int n = blockIdx.x;
    for (int i = threadIdx.x; i < 4608; i += 256) in_s[i] = y1[n * 4608 + i];
    __syncthreads();
    int oc = threadIdx.x >> 2;
    int q  = threadIdx.x & 3;                      // output row oy
    const float* wp = w2 + oc * 800;
    float a0, a1, a2, a3;
    a0 = a1 = a2 = a3 = b2[oc];
    for (int ic = 0; ic < 32; ++ic) {
        const float* base = in_s + ic * 144 + q * 24;   // input row 2*oy
        const float* wi = wp + ic * 25;
        float wreg[25];
#pragma unroll
        for (int t = 0; t < 25; ++t) wreg[t] = wi[t];
#pragma unroll
        for (int ky = 0; ky < 5; ++ky) {
            const float* rowp = base + ky * 12;
            float4 v0 = *(const float4*)(rowp);
            float4 v1 = *(const float4*)(rowp + 4);
            float4 v2 = *(const float4*)(rowp + 8);
            float r[12] = {v0.x, v0.y, v0.z, v0.w, v1.x, v1.y, v1.z, v1.w,
                           v2.x, v2.y, v2.z, v2.w};
#pragma unroll
            for (int kx = 0; kx < 5; ++kx) {
                float wv = wreg[ky * 5 + kx];
                a0 = fmaf(wv, r[kx],     a0);
                a1 = fmaf(wv, r[2 + kx], a1);
                a2 = fmaf(wv, r[4 + kx], a2);
                a3 = fmaf(wv, r[6 + kx], a3);
            }
        }
    }
    float* dst = y2 + (n * 64 + oc) * 16 + q * 4;  // (n, oc, oy, ox) == flat fc order
    dst[0] = fmaxf(a0, 0.0f);
    dst[1] = fmaxf(a1, 0.0f);
    dst[2] = fmaxf(a2, 0.0f);
    dst[3] = fmaxf(a3, 0.0f);
}

// ---------------------------------------------------------------------------
// K3: fc  feat(1024,128) = y2(1024,1024) @ fcwT(1024,128) + fc_b  (no relu)
// Tiled GEMM: 8 rows x 128 cols per block, BK=32. grid = 128 blocks.
// ---------------------------------------------------------------------------
__global__ __launch_bounds__(256) void k_fc(const float* __restrict__ y2,
                                            const float* __restrict__ fcwT,
                                            const float* __restrict__ fc_b,
                                            float* __restrict__ feat) {
    __shared__ float As[8][33];
    __shared__ float Bs[32][128];
    int row0 = blockIdx.x * 8;
    int tx = threadIdx.x & 127;                    // s
    int h  = threadIdx.x >> 7;                     // 0..1 -> rows h*4..h*4+3
    float acc[4] = {0.f, 0.f, 0.f, 0.f};
    for (int k0 = 0; k0 < 1024; k0 += 32) {
        {
            int i = threadIdx.x;                   // 256 == 8*32
            int r = i >> 5, c = i & 31;
            As[r][c] = y2[(row0 + r) * 1024 + k0 + c];
        }
        for (int i = threadIdx.x; i < 4096; i += 256) {
            int r = i >> 7, s = i & 127;
            Bs[r][s] = fcwT[(k0 + r) * 128 + s];
        }
        __syncthreads();
#pragma unroll
        for (int kk = 0; kk < 32; ++kk) {
            float bv = Bs[kk][tx];
#pragma unroll
            for (int u = 0; u < 4; ++u) acc[u] = fmaf(As[h * 4 + u][kk], bv, acc[u]);
        }
        __syncthreads();
    }
    float bias = fc_b[tx];
#pragma unroll
    for (int u = 0; u < 4; ++u)
        feat[(row0 + h * 4 + u) * 128 + tx] = acc[u] + bias;
}

// ---------------------------------------------------------------------------
// K4: per-(b,d) stats S=sum_i f, t=sum_i f^2; then per-(b,s) scalar terms
//   dconst = sum_d (Cct*t + CcA*S^2),  W = sum_d (Cwt*t + CwA*S^2)
// grid = 16 (b), block = 128 (d / s).
// ---------------------------------------------------------------------------
__global__ __launch_bounds__(128) void k_stats(const float* __restrict__ feat,
                                               const float* __restrict__ Cct,
                                               const float* __restrict__ CcA,
                                               const float* __restrict__ Cwt,
                                               const float* __restrict__ CwA,
                                               float* __restrict__ Sv, float* __restrict__ Tv,
                                               float* __restrict__ dconst, float* __restrict__ W_) {
    __shared__ float Tsh[128], Ash[128];
    int b = blockIdx.x, d = threadIdx.x;
    const float* f = feat + b * 64 * 128 + d;
    float s = 0.f, t = 0.f;
    for (int i = 0; i < 64; ++i) {
        float v = f[i * 128];
        s += v;
        t = fmaf(v, v, t);
    }
    Sv[b * 128 + d] = s;
    Tv[b * 128 + d] = t;
    Tsh[d] = t;
    Ash[d] = s * s;
    __syncthreads();
    int ss = threadIdx.x;
    float dc = 0.f, wv = 0.f;
#pragma unroll 4
    for (int d2 = 0; d2 < 128; ++d2) {
        float tt = Tsh[d2], aa = Ash[d2];
        dc = fmaf(Cct[d2 * 128 + ss], tt, fmaf(CcA[d2 * 128 + ss], aa, dc));
        wv = fmaf(Cwt[d2 * 128 + ss], tt, fmaf(CwA[d2 * 128 + ss], aa, wv));
    }
    dconst[b * 128 + ss] = dc;
    W_[b * 128 + ss] = wv;
}

// ---------------------------------------------------------------------------
// K5: D/U/V vectors: for each (b,i,s):
//   D = sum_d Cdg*g + Cdr*r ; U = sum_d Cug*g + Cur*r ; V = sum_d Cvg*g + Cvr*r
// with g = f^2, r = f*S. grid = 128 blocks (16 b x 8 row-groups of 8 rows).
// ---------------------------------------------------------------------------
__global__ __launch_bounds__(256) void k_duv(const float* __restrict__ feat,
                                             const float* __restrict__ Sv,
                                             const float* __restrict__ Cdg, const float* __restrict__ Cdr,
                                             const float* __restrict__ Cug, const float* __restrict__ Cur,
                                             const float* __restrict__ Cvg, const float* __restrict__ Cvr,
                                             float* __restrict__ D_, float* __restrict__ U_,
                                             float* __restrict__ V_) {
    __shared__ float fsh[8][128];
    __shared__ float Ssh[128];
    int b = blockIdx.x >> 3, ig = blockIdx.x & 7;
    int n0 = b * 64 + ig * 8;
    for (int i = threadIdx.x; i < 1024; i += 256) {
        int r = i >> 7, d = i & 127;
        fsh[r][d] = feat[(n0 + r) * 128 + d];
    }
    if (threadIdx.x < 128) Ssh[threadIdx.x] = Sv[b * 128 + threadIdx.x];
    __syncthreads();
    int s = threadIdx.x & 127, h = threadIdx.x >> 7;   // h -> rows h*4..h*4+3
    float aD[4] = {0, 0, 0, 0}, aU[4] = {0, 0, 0, 0}, aV[4] = {0, 0, 0, 0};
#pragma unroll 4
    for (int d = 0; d < 128; ++d) {
        float cdg = Cdg[d * 128 + s], cdr = Cdr[d * 128 + s];
        float cug = Cug[d * 128 + s], cur = Cur[d * 128 + s];
        float cvg = Cvg[d * 128 + s], cvr = Cvr[d * 128 + s];
        float sd = Ssh[d];
#pragma unroll
        for (int j = 0; j < 4; ++j) {
            float fv = fsh[h * 4 + j][d];
            float g = fv * fv, rr = fv * sd;
            aD[j] = fmaf(cdg, g, fmaf(cdr, rr, aD[j]));
            aU[j] = fmaf(cug, g, fmaf(cur, rr, aU[j]));
            aV[j] = fmaf(cvg, g, fmaf(cvr, rr, aV[j]));
        }
    }
#pragma unroll
    for (int j = 0; j < 4; ++j) {
        int n = n0 + h * 4 + j;
        D_[n * 128 + s] = aD[j];
        U_[n * 128 + s] = aU[j];
        V_[n * 128 + s] = aV[j];
    }
}

// ---------------------------------------------------------------------------
// K6 (main): one block per (b,s). PP[i,j] = sum_d a[s,d] f_i f_j computed as a
// 64x64x128 in-LDS matmul (4x4 register tile/thread), then fused
// +U[i]+V[j]+W+eq_bias (+diag terms on i==j), ReLU, mean -> out1[b,s].
// LDS rows are XOR-swizzled at float4-slot granularity: row stride stays 128
// (pow2), slot c -> c ^ ((r>>2)&7), making the stride-4-row float4 reads
// 2-way (free) instead of 8..16-way bank conflicts.
// ---------------------------------------------------------------------------
#define FS_IDX(r, d) (((r) << 7) + (((((d) >> 2) ^ (((r) >> 2) & 7))) << 2) + ((d) & 3))

__global__ __launch_bounds__(256) void k_main(const float* __restrict__ feat,
                                              const float* __restrict__ Ca,
                                              const float* __restrict__ D_,
                                              const float* __restrict__ U_,
                                              const float* __restrict__ V_,
                                              const float* __restrict__ dconst,
                                              const float* __restrict__ W_,
                                              const float* __restrict__ eq_bias,
                                              const float* __restrict__ diag_bias,
                                              float* __restrict__ out1) {
    __shared__ alignas(16) float fs[64 * 128];
    __shared__ alignas(16) float fa[64 * 128];
    __shared__ float ash[128];
    __shared__ float Uv[64], Vv[64], Dv[64];
    __shared__ float red[256];
    int b = blockIdx.x >> 7, s = blockIdx.x & 127;
    int tid = threadIdx.x;
    const float* fb = feat + b * 64 * 128;
    for (int i = tid; i < 8192; i += 256) {
        int r = i >> 7, d = i & 127;
        fs[FS_IDX(r, d)] = fb[i];
    }
    if (tid < 128) ash[tid] = Ca[s * 128 + tid];
    if (tid < 64) {
        Uv[tid] = U_[(b * 64 + tid) * 128 + s];
        Vv[tid] = V_[(b * 64 + tid) * 128 + s];
        Dv[tid] = D_[(b * 64 + tid) * 128 + s];
    }
    __syncthreads();
    for (int i = tid; i < 8192; i += 256) {
        int r = i >> 7, d = i & 127;
        int ii = FS_IDX(r, d);
        fa[ii] = fs[ii] * ash[d];
    }
    __syncthreads();
    int tx = tid & 15, ty = tid >> 4;              // rows i=4ty.., cols j=4tx..
    float acc[4][4] = {};
#pragma unroll 2
    for (int d = 0; d < 128; d += 4) {
        float4 ai[4], bj[4];
#pragma unroll
        for (int u = 0; u < 4; ++u) ai[u] = *(const float4*)&fa[FS_IDX(ty * 4 + u, d)];
#pragma unroll
        for (int v = 0; v < 4; ++v) bj[v] = *(const float4*)&fs[FS_IDX(tx * 4 + v, d)];
#pragma unroll
        for (int u = 0; u < 4; ++u)
#pragma unroll
            for (int v = 0; v < 4; ++v)
                acc[u][v] += ai[u].x * bj[v].x + ai[u].y * bj[v].y +
                             ai[u].z * bj[v].z + ai[u].w * bj[v].w;
    }
    float Wtot = W_[b * 128 + s] + eq_bias[s];
    float Dcb = dconst[b * 128 + s] + diag_bias[s];
    float psum = 0.0f;
#pragma unroll
    for (int u = 0; u < 4; ++u) {
        int i = ty * 4 + u;
#pragma unroll
        for (int v = 0; v < 4; ++v) {
            int j = tx * 4 + v;
            float val = acc[u][v] + Uv[i] + Vv[j] + Wtot;
            if (i == j) val += Dv[i] + Dcb;
            psum += fmaxf(val, 0.0f);
        }
    }
    red[tid] = psum;
    __syncthreads();
    for (int off = 128; off > 0; off >>= 1) {
        if (tid < off) red[tid] += red[tid + off];
        __syncthreads();
    }
    if (tid == 0) out1[b * 128 + s] = red[0] * (1.0f / 4096.0f);
}

// K7: d_out[b] = sum_s relu(out1[b,s]) * out_w[s] + out_b
__global__ __launch_bounds__(128) void k_final(const float* __restrict__ out1,
                                               const float* __restrict__ out_w,
                                               const float* __restrict__ out_b,
                                               float* __restrict__ out) {
    __shared__ float red[128];
    int b = blockIdx.x, s = threadIdx.x;
    red[s] = fmaxf(out1[b * 128 + s], 0.0f) * out_w[s];
    __syncthreads();
    for (int off = 64; off > 0; off >>= 1) {
        if (s < off) red[s] += red[s + off];
        __syncthreads();
    }
    if (s == 0) out[b] = red[0] + out_b[0];
}

extern "C" void kernel_launch(void* const* d_in, const int* in_sizes, int n_in,
                              void* d_out, int out_size, void* d_ws, size_t ws_size,
                              hipStream_t stream) {
    const float* x      = (const float*)d_in[0];
    const float* w1     = (const float*)d_in[1];
    const float* b1     = (const float*)d_in[2];
    const float* w2     = (const float*)d_in[3];
    const float* b2     = (const float*)d_in[4];
    const float* fc_w   = (const float*)d_in[5];
    const float* fc_b   = (const float*)d_in[6];
    const float* coeffs = (const float*)d_in[7];
    const float* eqb    = (const float*)d_in[8];
    const float* dgb    = (const float*)d_in[9];
    const float* out_w  = (const float*)d_in[10];
    const float* out_b  = (const float*)d_in[11];

    float* ws = (float*)d_ws;   // total ~26.5 MB of fp32 scratch
    float* y1   = ws; ws += 4718592;   // (1024,32,12,12)
    float* y2   = ws; ws += 1048576;   // (1024,64,4,4) == fc input flat
    float* feat = ws; ws += 131072;    // (1024,128)
    float* fcwT = ws; ws += 131072;    // (1024,128)
    float* Sv   = ws; ws += 2048;
    float* Tv   = ws; ws += 2048;
    float* Ca   = ws; ws += 16384;
    float* Cdg  = ws; ws += 16384;
    float* Cdr  = ws; ws += 16384;
    float* Cug  = ws; ws += 16384;
    float* Cur  = ws; ws += 16384;
    float* Cvg  = ws; ws += 16384;
    float* Cvr  = ws; ws += 16384;
    float* Cct  = ws; ws += 16384;
    float* CcA  = ws; ws += 16384;
    float* Cwt  = ws; ws += 16384;
    float* CwA  = ws; ws += 16384;
    float* D_   = ws; ws += 131072;
    float* U_   = ws; ws += 131072;
    float* V_   = ws; ws += 131072;
    float* dco  = ws; ws += 2048;
    float* W_   = ws; ws += 2048;
    float* out1 = ws; ws += 2048;

    k_prep<<<64, 256, 0, stream>>>(coeffs, Ca, Cdg, Cdr, Cug, Cur, Cvg, Cvr,
                                   Cct, CcA, Cwt, CwA);
    k_fcwT<<<512, 256, 0, stream>>>(fc_w, fcwT);
    k_conv1<<<18432, 256, 0, stream>>>(x, w1, b1, y1);
    k_conv2<<<1024, 256, 0, stream>>>(y1, w2, b2, y2);
    k_fc<<<128, 256, 0, stream>>>(y2, fcwT, fc_b, feat);
    k_stats<<<16, 128, 0, stream>>>(feat, Cct, CcA, Cwt, CwA, Sv, Tv, dco, W_);
    k_duv<<<128, 256, 0, stream>>>(feat, Sv, Cdg, Cdr, Cug, Cur, Cvg, Cvr, D_, U_, V_);
    k_main<<<2048, 256, 0, stream>>>(feat, Ca, D_, U_, V_, dco, W_, eqb, dgb, out1);
    k_final<<<16, 128, 0, stream>>>(out1, out_w, out_b, (float*)d_out);
}

// Round 4
// 214.182 us; speedup vs baseline: 1.3942x; 1.3942x over previous
//
#include <hip/hip_runtime.h>

// B=16, K=64 -> N=1024 images 28x28; conv1: 1->32ch 12x12; conv2: 32->64ch 4x4
// FLAT=1024, HID=D=128, OUT=S=128, m=64.
//
// Decomposition (P = f f^T symmetric, so rows==cols):
//   out[b,s,i,j] = PP[i,j] + U[i] + V[j] + W + delta_ij*(D[i] + dconst)
//   PP = sum_d a[s,d] f_i f_j ; U/V/D from g=f^2, r=f*S ; W,dconst from t=sum f^2, A=S^2

// ---------------------------------------------------------------------------
// K0: one-time prep. Coeff combine -> [s][d]-major matrices; fc_w transpose;
// w2 transpose to [ic*25+t][oc] (so conv2 weight loads are 1 cache line/wave);
// zero d_out (k_main2 accumulates into it atomically).
// ---------------------------------------------------------------------------
__global__ __launch_bounds__(256) void k_prep(
        const float* __restrict__ coeffs, const float* __restrict__ fc_w,
        const float* __restrict__ w2,
        float* __restrict__ CaT,  float* __restrict__ CdgT, float* __restrict__ CdrT,
        float* __restrict__ CugT, float* __restrict__ CurT,
        float* __restrict__ CvgT, float* __restrict__ CvrT,
        float* __restrict__ CctT, float* __restrict__ CcAT,
        float* __restrict__ CwtT, float* __restrict__ CwAT,
        float* __restrict__ fcwT, float* __restrict__ w2T,
        float* __restrict__ dout) {
    int idx = blockIdx.x * 256 + threadIdx.x;
    if (idx < 16384) {
        int d = idx >> 7, s = idx & 127;
        const float* c = coeffs + idx * 15;        // coeffs[d][s][p]
        const float im = 1.0f / 64.0f, im2 = 1.0f / 4096.0f;
        int t = s * 128 + d;                       // [s][d] layout
        CaT[t]  = c[9] + c[10];
        CdgT[t] = c[0];
        CdrT[t] = (c[2] + c[3]) * im;
        CurT[t] = (c[5] + c[6]) * im;
        CugT[t] = c[11];
        CvrT[t] = (c[7] + c[8]) * im;
        CvgT[t] = c[12];
        CctT[t] = c[1] * im;
        CcAT[t] = c[4] * im2;
        CwtT[t] = c[13] * im;
        CwAT[t] = c[14] * im2;
        if (idx < 16) dout[idx] = 0.0f;
    } else if (idx < 16384 + 131072) {
        int e = idx - 16384;                       // e = s*1024 + k
        int s = e >> 10, k = e & 1023;
        fcwT[k * 128 + s] = fc_w[e];
    } else if (idx < 16384 + 131072 + 51200) {
        int e = idx - 147456;                      // e = r*64 + oc, r = ic*25+t
        int oc = e & 63, r = e >> 6;
        w2T[e] = w2[oc * 800 + r];
    }
}

// ---------------------------------------------------------------------------
// K1: fused conv1 + conv2 + fc, one block per image n.
// x (3 KB) -> LDS; conv1 -> c1 LDS (18 KB); conv2 -> ysh LDS (4 KB); fc -> feat.
// ---------------------------------------------------------------------------
__global__ __launch_bounds__(256) void k_convfc(
        const float* __restrict__ x,  const float* __restrict__ w1,
        const float* __restrict__ b1, const float* __restrict__ w2T,
        const float* __restrict__ b2, const float* __restrict__ fcwT,
        const float* __restrict__ fc_b, float* __restrict__ feat) {
    __shared__ alignas(16) float xs[784];
    __shared__ float w1s[800];
    __shared__ alignas(16) float c1[32 * 144];
    __shared__ alignas(16) float ysh[1024];
    __shared__ float red[256];
    int n = blockIdx.x, tid = threadIdx.x;

    for (int i = tid; i < 784; i += 256) xs[i] = x[n * 784 + i];
    for (int i = tid; i < 800; i += 256) w1s[i] = w1[i];
    __syncthreads();

    // conv1: 32 oc x 12 x 12 = 4608 outputs, 18 per thread
    for (int o = tid; o < 4608; o += 256) {
        int oc = o / 144, pos = o - oc * 144;
        int oy = pos / 12, ox = pos - oy * 12;
        const float* bp = xs + oy * 56 + ox * 2;   // (oy*2)*28 + ox*2
        const float* wp = w1s + oc * 25;
        float acc = b1[oc];
#pragma unroll
        for (int ky = 0; ky < 5; ++ky)
#pragma unroll
            for (int kx = 0; kx < 5; ++kx)
                acc = fmaf(bp[ky * 28 + kx], wp[ky * 5 + kx], acc);
        c1[o] = fmaxf(acc, 0.0f);
    }
    __syncthreads();

    // conv2: thread = (oc = tid>>2, oy = tid&3), 4 ox outputs each
    {
        int oc = tid >> 2, q = tid & 3;
        float a0, a1, a2, a3;
        a0 = a1 = a2 = a3 = b2[oc];
        for (int ic = 0; ic < 32; ++ic) {
            const float* base = c1 + ic * 144 + q * 24;
            float wreg[25];
#pragma unroll
            for (int t = 0; t < 25; ++t) wreg[t] = w2T[(ic * 25 + t) * 64 + oc];
#pragma unroll
            for (int ky = 0; ky < 5; ++ky) {
                const float* rowp = base + ky * 12;
                float4 v0 = *(const float4*)(rowp);
                float4 v1 = *(const float4*)(rowp + 4);
                float4 v2 = *(const float4*)(rowp + 8);
                float r[12] = {v0.x, v0.y, v0.z, v0.w, v1.x, v1.y, v1.z, v1.w,
                               v2.x, v2.y, v2.z, v2.w};
#pragma unroll
                for (int kx = 0; kx < 5; ++kx) {
                    float wv = wreg[ky * 5 + kx];
                    a0 = fmaf(wv, r[kx],     a0);
                    a1 = fmaf(wv, r[2 + kx], a1);
                    a2 = fmaf(wv, r[4 + kx], a2);
                    a3 = fmaf(wv, r[6 + kx], a3);
                }
            }
        }
        int yb = oc * 16 + q * 4;                  // flat (oc, oy, ox) == fc k-order
        ysh[yb]     = fmaxf(a0, 0.0f);
        ysh[yb + 1] = fmaxf(a1, 0.0f);
        ysh[yb + 2] = fmaxf(a2, 0.0f);
        ysh[yb + 3] = fmaxf(a3, 0.0f);
    }
    __syncthreads();

    // fc: feat[n,s] = sum_k ysh[k] * fcwT[k*128+s] + fc_b[s]; 2 threads per s
    {
        int s = tid & 127, h = tid >> 7;
        const float* bp2 = fcwT + (h * 512) * 128 + s;
        const float* yrow = ysh + h * 512;
        float acc = 0.0f;
#pragma unroll 8
        for (int k = 0; k < 512; ++k) acc = fmaf(yrow[k], bp2[k * 128], acc);
        red[tid] = acc;
        __syncthreads();
        if (h == 0) feat[n * 128 + s] = red[s] + red[s + 128] + fc_b[s];
    }
}

// ---------------------------------------------------------------------------
// K2: one block per (b,s). Stages feat[b] (32KB, FS_IDX-swizzled), computes
// S/T stats, dconst/W scalars, D/U/V vectors for its own s, the 64x64x128
// weighted-Gram matmul, fused epilogue + mean, then relu*out_w -> atomicAdd.
// Swizzle: slot c -> c ^ ((r>>2)&7) keeps stride-4-row float4 reads ~2-way.
// ---------------------------------------------------------------------------
#define FS_IDX(r, d) (((r) << 7) + (((((d) >> 2) ^ (((r) >> 2) & 7))) << 2) + ((d) & 3))

__global__ __launch_bounds__(256) void k_main2(
        const float* __restrict__ feat,
        const float* __restrict__ CaT,  const float* __restrict__ CdgT,
        const float* __restrict__ CdrT, const float* __restrict__ CugT,
        const float* __restrict__ CurT, const float* __restrict__ CvgT,
        const float* __restrict__ CvrT, const float* __restrict__ CctT,
        const float* __restrict__ CcAT, const float* __restrict__ CwtT,
        const float* __restrict__ CwAT,
        const float* __restrict__ eq_bias, const float* __restrict__ diag_bias,
        const float* __restrict__ out_w,   const float* __restrict__ out_b,
        float* __restrict__ dout) {
    __shared__ alignas(16) float fs[8192];
    __shared__ alignas(16) float fa[8192];
    __shared__ float ash[128];
    __shared__ alignas(16) float Ssh[128];
    __shared__ float Uv[64], Vv[64], Dv[64];
    __shared__ float red[4];
    __shared__ float parts[4];                     // dc0, dc1, w0, w1
    int b = blockIdx.x >> 7, s = blockIdx.x & 127;
    int tid = threadIdx.x;
    const float* fb = feat + b * 8192;

    // phase 0: stage
    for (int i = tid; i < 8192; i += 256) {
        int r = i >> 7, d = i & 127;
        fs[FS_IDX(r, d)] = fb[i];
    }
    if (tid < 128) ash[tid] = CaT[s * 128 + tid];
    __syncthreads();

    // phase 1: fa = fs * a[s,:]  (all threads)
    for (int i = tid; i < 8192; i += 256) {
        int r = i >> 7, d = i & 127;
        int ii = FS_IDX(r, d);
        fa[ii] = fs[ii] * ash[d];
    }
    // phase 2: S/T per d + dconst/W reduction (threads 0..127 = waves 0,1)
    if (tid < 128) {
        int d = tid;
        float sv = 0.0f, tv = 0.0f;
        for (int r = 0; r < 64; ++r) {
            float v = fs[FS_IDX(r, d)];
            sv += v;
            tv = fmaf(v, v, tv);
        }
        Ssh[d] = sv;
        float av = sv * sv;
        float dcv = fmaf(CctT[s * 128 + d], tv, CcAT[s * 128 + d] * av);
        float wvv = fmaf(CwtT[s * 128 + d], tv, CwAT[s * 128 + d] * av);
#pragma unroll
        for (int m = 1; m < 64; m <<= 1) {
            dcv += __shfl_xor(dcv, m);
            wvv += __shfl_xor(wvv, m);
        }
        if ((tid & 63) == 0) {
            parts[tid >> 6] = dcv;
            parts[2 + (tid >> 6)] = wvv;
        }
    }
    __syncthreads();

    // phase 3: D/U/V for this s. thread (ty=tid>>4, tx=tid&15):
    // rows i = ty*4+u, d-range = tx*8 .. tx*8+7; shfl-reduce over tx.
    int tx = tid & 15, ty = tid >> 4;
    {
        int d0 = tx * 8;
        const float* cb = CdgT + s * 128 + d0;
        float4 cg0 = *(const float4*)(cb);
        float4 cg1 = *(const float4*)(cb + 4);
        cb = CdrT + s * 128 + d0;
        float4 cr0 = *(const float4*)(cb);
        float4 cr1 = *(const float4*)(cb + 4);
        cb = CugT + s * 128 + d0;
        float4 ug0 = *(const float4*)(cb);
        float4 ug1 = *(const float4*)(cb + 4);
        cb = CurT + s * 128 + d0;
        float4 ur0 = *(const float4*)(cb);
        float4 ur1 = *(const float4*)(cb + 4);
        cb = CvgT + s * 128 + d0;
        float4 vg0 = *(const float4*)(cb);
        float4 vg1 = *(const float4*)(cb + 4);
        cb = CvrT + s * 128 + d0;
        float4 vr0 = *(const float4*)(cb);
        float4 vr1 = *(const float4*)(cb + 4);
        float4 sv0 = *(const float4*)&Ssh[d0];
        float4 sv1 = *(const float4*)&Ssh[d0 + 4];
        float cg[8] = {cg0.x, cg0.y, cg0.z, cg0.w, cg1.x, cg1.y, cg1.z, cg1.w};
        float cr[8] = {cr0.x, cr0.y, cr0.z, cr0.w, cr1.x, cr1.y, cr1.z, cr1.w};
        float ug[8] = {ug0.x, ug0.y, ug0.z, ug0.w, ug1.x, ug1.y, ug1.z, ug1.w};
        float ur[8] = {ur0.x, ur0.y, ur0.z, ur0.w, ur1.x, ur1.y, ur1.z, ur1.w};
        float vg[8] = {vg0.x, vg0.y, vg0.z, vg0.w, vg1.x, vg1.y, vg1.z, vg1.w};
        float vr[8] = {vr0.x, vr0.y, vr0.z, vr0.w, vr1.x, vr1.y, vr1.z, vr1.w};
        float sv[8] = {sv0.x, sv0.y, sv0.z, sv0.w, sv1.x, sv1.y, sv1.z, sv1.w};
        float pD[4], pU[4], pV[4];
#pragma unroll
        for (int u = 0; u < 4; ++u) {
            int i = ty * 4 + u;
            float4 fA = *(const float4*)&fs[FS_IDX(i, d0)];
            float4 fB = *(const float4*)&fs[FS_IDX(i, d0 + 4)];
            float fv[8] = {fA.x, fA.y, fA.z, fA.w, fB.x, fB.y, fB.z, fB.w};
            float aD = 0.0f, aU = 0.0f, aV = 0.0f;
#pragma unroll
            for (int e = 0; e < 8; ++e) {
                float g  = fv[e] * fv[e];
                float rr = fv[e] * sv[e];
                aD = fmaf(cg[e], g, fmaf(cr[e], rr, aD));
                aU = fmaf(ug[e], g, fmaf(ur[e], rr, aU));
                aV = fmaf(vg[e], g, fmaf(vr[e], rr, aV));
            }
            pD[u] = aD; pU[u] = aU; pV[u] = aV;
        }
#pragma unroll
        for (int m = 1; m < 16; m <<= 1) {
#pragma unroll
            for (int u = 0; u < 4; ++u) {
                pD[u] += __shfl_xor(pD[u], m);
                pU[u] += __shfl_xor(pU[u], m);
                pV[u] += __shfl_xor(pV[u], m);
            }
        }
        if (tx == 0) {
#pragma unroll
            for (int u = 0; u < 4; ++u) {
                Dv[ty * 4 + u] = pD[u];
                Uv[ty * 4 + u] = pU[u];
                Vv[ty * 4 + u] = pV[u];
            }
        }
    }
    __syncthreads();

    // phase 4: 64x64x128 matmul, 4x4 tile per thread
    float acc[4][4] = {};
#pragma unroll 2
    for (int d = 0; d < 128; d += 4) {
        float4 ai[4], bj[4];
#pragma unroll
        for (int u = 0; u < 4; ++u) ai[u] = *(const float4*)&fa[FS_IDX(ty * 4 + u, d)];
#pragma unroll
        for (int v = 0; v < 4; ++v) bj[v] = *(const float4*)&fs[FS_IDX(tx * 4 + v, d)];
#pragma unroll
        for (int u = 0; u < 4; ++u)
#pragma unroll
            for (int v = 0; v < 4; ++v)
                acc[u][v] += ai[u].x * bj[v].x + ai[u].y * bj[v].y +
                             ai[u].z * bj[v].z + ai[u].w * bj[v].w;
    }

    // phase 5: epilogue + block reduce + atomic
    float sDc = parts[0] + parts[1] + diag_bias[s];
    float sW  = parts[2] + parts[3] + eq_bias[s];
    float psum = 0.0f;
#pragma unroll
    for (int u = 0; u < 4; ++u) {
        int i = ty * 4 + u;
#pragma unroll
        for (int v = 0; v < 4; ++v) {
            int j = tx * 4 + v;
            float val = acc[u][v] + Uv[i] + Vv[j] + sW;
            if (i == j) val += Dv[i] + sDc;
            psum += fmaxf(val, 0.0f);
        }
    }
#pragma unroll
    for (int m = 1; m < 64; m <<= 1) psum += __shfl_xor(psum, m);
    if ((tid & 63) == 0) red[tid >> 6] = psum;
    __syncthreads();
    if (tid == 0) {
        float tot = red[0] + red[1] + red[2] + red[3];
        float o1 = tot * (1.0f / 4096.0f);
        float o = fmaxf(o1, 0.0f) * out_w[s];
        if (s == 0) o += out_b[0];
        atomicAdd(dout + b, o);
    }
}

extern "C" void kernel_launch(void* const* d_in, const int* in_sizes, int n_in,
                              void* d_out, int out_size, void* d_ws, size_t ws_size,
                              hipStream_t stream) {
    const float* x      = (const float*)d_in[0];
    const float* w1     = (const float*)d_in[1];
    const float* b1     = (const float*)d_in[2];
    const float* w2     = (const float*)d_in[3];
    const float* b2     = (const float*)d_in[4];
    const float* fc_w   = (const float*)d_in[5];
    const float* fc_b   = (const float*)d_in[6];
    const float* coeffs = (const float*)d_in[7];
    const float* eqb    = (const float*)d_in[8];
    const float* dgb    = (const float*)d_in[9];
    const float* out_w  = (const float*)d_in[10];
    const float* out_b  = (const float*)d_in[11];

    float* ws = (float*)d_ws;
    float* feat = ws; ws += 131072;    // (1024,128)
    float* fcwT = ws; ws += 131072;    // (1024,128)
    float* w2T  = ws; ws += 51200;     // (800,64)
    float* CaT  = ws; ws += 16384;
    float* CdgT = ws; ws += 16384;
    float* CdrT = ws; ws += 16384;
    float* CugT = ws; ws += 16384;
    float* CurT = ws; ws += 16384;
    float* CvgT = ws; ws += 16384;
    float* CvrT = ws; ws += 16384;
    float* CctT = ws; ws += 16384;
    float* CcAT = ws; ws += 16384;
    float* CwtT = ws; ws += 16384;
    float* CwAT = ws; ws += 16384;

    k_prep<<<776, 256, 0, stream>>>(coeffs, fc_w, w2,
                                    CaT, CdgT, CdrT, CugT, CurT, CvgT, CvrT,
                                    CctT, CcAT, CwtT, CwAT, fcwT, w2T,
                                    (float*)d_out);
    k_convfc<<<1024, 256, 0, stream>>>(x, w1, b1, w2T, b2, fcwT, fc_b, feat);
    k_main2<<<2048, 256, 0, stream>>>(feat, CaT, CdgT, CdrT, CugT, CurT,
                                      CvgT, CvrT, CctT, CcAT, CwtT, CwAT,
                                      eqb, dgb, out_w, out_b, (float*)d_out);
}

// Round 5
// 206.493 us; speedup vs baseline: 1.4461x; 1.0372x over previous
//
#include <hip/hip_runtime.h>

// B=16, K=64 -> N=1024 images 28x28; conv1: 1->32ch 12x12; conv2: 32->64ch 4x4
// FLAT=1024, HID=D=128, OUT=S=128, m=64.
//
// out[b,s,i,j] = PP[i,j] + U[i] + V[j] + W + delta_ij*(D[i] + dconst)
// PP = sum_d a[s,d] f_i f_j ; U/V/D from g=f^2, r=f*S ; W,dconst from t=sum f^2, A=S^2

#define FS_IDX(r, d) (((r) << 7) + (((((d) >> 2) ^ (((r) >> 2) & 7))) << 2) + ((d) & 3))

// ---------------------------------------------------------------------------
// K0: one-time prep. Coeff combine -> [s][d] matrices; fc_w transpose ->
// fcwT[k][s]; w2 reshape -> w2R[oc][ky][kx][ic] (ic-contiguous for float4
// loads over a thread's 4 ic); zero d_out.
// ---------------------------------------------------------------------------
__global__ __launch_bounds__(256) void k_prep(
        const float* __restrict__ coeffs, const float* __restrict__ fc_w,
        const float* __restrict__ w2,
        float* __restrict__ CaT,  float* __restrict__ CdgT, float* __restrict__ CdrT,
        float* __restrict__ CugT, float* __restrict__ CurT,
        float* __restrict__ CvgT, float* __restrict__ CvrT,
        float* __restrict__ CctT, float* __restrict__ CcAT,
        float* __restrict__ CwtT, float* __restrict__ CwAT,
        float* __restrict__ fcwT, float* __restrict__ w2R,
        float* __restrict__ dout) {
    int idx = blockIdx.x * 256 + threadIdx.x;
    if (idx < 16384) {
        int d = idx >> 7, s = idx & 127;
        const float* c = coeffs + idx * 15;        // coeffs[d][s][p]
        const float im = 1.0f / 64.0f, im2 = 1.0f / 4096.0f;
        int t = s * 128 + d;                       // [s][d] layout
        CaT[t]  = c[9] + c[10];
        CdgT[t] = c[0];
        CdrT[t] = (c[2] + c[3]) * im;
        CurT[t] = (c[5] + c[6]) * im;
        CugT[t] = c[11];
        CvrT[t] = (c[7] + c[8]) * im;
        CvgT[t] = c[12];
        CctT[t] = c[1] * im;
        CcAT[t] = c[4] * im2;
        CwtT[t] = c[13] * im;
        CwAT[t] = c[14] * im2;
        if (idx < 16) dout[idx] = 0.0f;
    } else if (idx < 147456) {
        int e = idx - 16384;                       // e = s*1024 + k
        int s = e >> 10, k = e & 1023;
        fcwT[k * 128 + s] = fc_w[e];
    } else if (idx < 198656) {
        int e = idx - 147456;                      // e = ((oc*5+ky)*5+kx)*32+ic
        int ic = e & 31;
        int q = e >> 5;
        int kx = q % 5, q2 = q / 5, ky = q2 % 5, oc = q2 / 5;
        w2R[e] = w2[oc * 800 + ic * 25 + ky * 5 + kx];
    }
}

// ---------------------------------------------------------------------------
// K1: fused conv1 + conv2 + fc, TWO images per block (512 blocks).
// conv1: thread=(oy,oc) computes a full 12-wide output row from float4 xs
// reads; writes TRANSPOSED c1T[pos][ic] so conv2 can read 4-ic float4s.
// conv2: thread=(ocg,icg): 2 oc x 16 outputs over 4 ic; c1T reads are 8
// distinct 16B segments/wave covering all 32 banks (conflict-free); weights
// via w2R float4 (1KB/instr); 3-shfl icg reduce.
// fc: thread=(kc,sg): float4 weights x 2 images (8 FMA per b128 load).
// ---------------------------------------------------------------------------
__global__ __launch_bounds__(256, 2) void k_convfc(
        const float* __restrict__ x,  const float* __restrict__ w1,
        const float* __restrict__ b1, const float* __restrict__ w2R,
        const float* __restrict__ b2, const float* __restrict__ fcwT,
        const float* __restrict__ fc_b, float* __restrict__ feat) {
    __shared__ alignas(16) float xs[1568];         // 2 x 784
    __shared__ alignas(16) float w1s[800];
    __shared__ alignas(16) float c1T[4608];        // [pos 144][ic 32]
    __shared__ alignas(16) float ysh[2][1024];
    __shared__ alignas(16) float ps[8][2][128];
    int tid = threadIdx.x;
    int n0 = blockIdx.x * 2;

    {   // stage both images + conv1 weights
        const float4* xsrc = (const float4*)(x + n0 * 784);
        float4* xdst = (float4*)xs;
        for (int i = tid; i < 392; i += 256) xdst[i] = xsrc[i];
        const float4* wsrc = (const float4*)w1;
        float4* wdst = (float4*)w1s;
        for (int i = tid; i < 200; i += 256) wdst[i] = wsrc[i];
    }
    __syncthreads();

    for (int img = 0; img < 2; ++img) {
        // ---- conv1: task = oy*32 + oc ----
        for (int task = tid; task < 384; task += 256) {
            int oy = task >> 5, oc = task & 31;
            const float* wp = w1s + oc * 25;
            float wr[25];
#pragma unroll
            for (int t = 0; t < 25; ++t) wr[t] = wp[t];
            float out[12];
            float bv = b1[oc];
#pragma unroll
            for (int ox = 0; ox < 12; ++ox) out[ox] = bv;
            const float* xb = xs + img * 784 + (oy * 2) * 28;
#pragma unroll
            for (int ky = 0; ky < 5; ++ky) {
                const float4* rp = (const float4*)(xb + ky * 28);
                float4 r0 = rp[0], r1 = rp[1], r2 = rp[2], r3 = rp[3];
                float4 r4 = rp[4], r5 = rp[5], r6 = rp[6];
                float rf[28] = {r0.x, r0.y, r0.z, r0.w, r1.x, r1.y, r1.z, r1.w,
                                r2.x, r2.y, r2.z, r2.w, r3.x, r3.y, r3.z, r3.w,
                                r4.x, r4.y, r4.z, r4.w, r5.x, r5.y, r5.z, r5.w,
                                r6.x, r6.y, r6.z, r6.w};
#pragma unroll
                for (int kx = 0; kx < 5; ++kx) {
                    float wv = wr[ky * 5 + kx];
#pragma unroll
                    for (int ox = 0; ox < 12; ++ox)
                        out[ox] = fmaf(rf[2 * ox + kx], wv, out[ox]);
                }
            }
#pragma unroll
            for (int ox = 0; ox < 12; ++ox)
                c1T[(oy * 12 + ox) * 32 + oc] = fmaxf(out[ox], 0.0f);
        }
        __syncthreads();

        // ---- conv2: tid = ocg*8 + icg ----
        {
            int icg = tid & 7, ocg = tid >> 3;     // icg: 4-ic group; ocg: oc pair
            int ic0 = icg * 4;
            float acc[2][16];
#pragma unroll
            for (int l = 0; l < 2; ++l)
#pragma unroll
                for (int p = 0; p < 16; ++p) acc[l][p] = 0.0f;
#pragma unroll
            for (int ky = 0; ky < 5; ++ky) {
                float4 wv[2][5];
#pragma unroll
                for (int l = 0; l < 2; ++l) {
                    int oc = ocg * 2 + l;
#pragma unroll
                    for (int kx = 0; kx < 5; ++kx)
                        wv[l][kx] = *(const float4*)&w2R[((oc * 5 + ky) * 5 + kx) * 32 + ic0];
                }
#pragma unroll
                for (int oyy = 0; oyy < 4; ++oyy) {
                    int y = 2 * oyy + ky;          // <= 10
                    float4 v[12];
#pragma unroll
                    for (int xx = 0; xx < 12; ++xx)
                        v[xx] = *(const float4*)&c1T[(y * 12 + xx) * 32 + ic0];
#pragma unroll
                    for (int l = 0; l < 2; ++l)
#pragma unroll
                        for (int ox = 0; ox < 4; ++ox) {
                            float s = acc[l][oyy * 4 + ox];
#pragma unroll
                            for (int kx = 0; kx < 5; ++kx) {
                                float4 vv = v[2 * ox + kx];
                                float4 ww = wv[l][kx];
                                s = fmaf(vv.x, ww.x, s);
                                s = fmaf(vv.y, ww.y, s);
                                s = fmaf(vv.z, ww.z, s);
                                s = fmaf(vv.w, ww.w, s);
                            }
                            acc[l][oyy * 4 + ox] = s;
                        }
                }
            }
#pragma unroll
            for (int m = 1; m < 8; m <<= 1)
#pragma unroll
                for (int l = 0; l < 2; ++l)
#pragma unroll
                    for (int p = 0; p < 16; ++p)
                        acc[l][p] += __shfl_xor(acc[l][p], m);
            if (icg == 0) {
#pragma unroll
                for (int l = 0; l < 2; ++l) {
                    int oc = ocg * 2 + l;
                    float bb = b2[oc];
#pragma unroll
                    for (int p = 0; p < 16; ++p)
                        ysh[img][oc * 16 + p] = fmaxf(acc[l][p] + bb, 0.0f);
                }
            }
        }
        __syncthreads();
    }

    // ---- fc: tid = kc*32 + sg ----
    {
        int sg = tid & 31, kc = tid >> 5;
        const float* yb0 = &ysh[0][kc * 128];
        const float* yb1 = &ysh[1][kc * 128];
        const float* wb = fcwT + kc * 128 * 128 + sg * 4;
        float4 a0 = {0.f, 0.f, 0.f, 0.f}, a1 = {0.f, 0.f, 0.f, 0.f};
#pragma unroll 4
        for (int i = 0; i < 128; ++i) {
            float4 w = *(const float4*)(wb + i * 128);
            float y0 = yb0[i], y1 = yb1[i];
            a0.x = fmaf(y0, w.x, a0.x); a0.y = fmaf(y0, w.y, a0.y);
            a0.z = fmaf(y0, w.z, a0.z); a0.w = fmaf(y0, w.w, a0.w);
            a1.x = fmaf(y1, w.x, a1.x); a1.y = fmaf(y1, w.y, a1.y);
            a1.z = fmaf(y1, w.z, a1.z); a1.w = fmaf(y1, w.w, a1.w);
        }
        *(float4*)&ps[kc][0][sg * 4] = a0;
        *(float4*)&ps[kc][1][sg * 4] = a1;
    }
    __syncthreads();
    {
        int img = tid >> 7, s = tid & 127;
        float acc = fc_b[s];
#pragma unroll
        for (int kc = 0; kc < 8; ++kc) acc += ps[kc][img][s];
        feat[(n0 + img) * 128 + s] = acc;
    }
}

// ---------------------------------------------------------------------------
// K2: one block per (b, s-quad): 512 blocks, 4 s each. Stages feat[b] once
// (FS_IDX swizzle), computes stats + dconst/W + D/U/V for 4 s, then the
// 64x64x128 Gram with a[s,d] folded in-register (12 b128 per 4d-step feeds
// 1280 FMA across the 4 s). Fused epilogue/mean/final-dot -> atomicAdd.
// ---------------------------------------------------------------------------
__global__ __launch_bounds__(256, 2) void k_main2(
        const float* __restrict__ feat,
        const float* __restrict__ CaT,  const float* __restrict__ CdgT,
        const float* __restrict__ CdrT, const float* __restrict__ CugT,
        const float* __restrict__ CurT, const float* __restrict__ CvgT,
        const float* __restrict__ CvrT, const float* __restrict__ CctT,
        const float* __restrict__ CcAT, const float* __restrict__ CwtT,
        const float* __restrict__ CwAT,
        const float* __restrict__ eq_bias, const float* __restrict__ diag_bias,
        const float* __restrict__ out_w,   const float* __restrict__ out_b,
        float* __restrict__ dout) {
    __shared__ alignas(16) float fs[8192];
    __shared__ alignas(16) float ash2[512];        // [d][sl]
    __shared__ alignas(16) float Ssh[128];
    __shared__ float Uv[4][64], Vv[4][64], Dv[4][64];
    __shared__ float parts[2][8];                  // [wave01][dc*4 | w*4]
    __shared__ float red[4][4];                    // [wave][sl]
    int b = blockIdx.x >> 5, sq = blockIdx.x & 31;
    int s0 = sq * 4;
    int tid = threadIdx.x;
    const float* fb = feat + b * 8192;

    // phase 0: stage
    for (int i = tid; i < 8192; i += 256) {
        int r = i >> 7, d = i & 127;
        fs[FS_IDX(r, d)] = fb[i];
    }
    for (int i = tid; i < 512; i += 256) {
        int d = i >> 2, sl = i & 3;
        ash2[d * 4 + sl] = CaT[(s0 + sl) * 128 + d];
    }
    __syncthreads();

    // phase 2: S/T per d + dconst/W partials (threads 0..127)
    if (tid < 128) {
        int d = tid;
        float sv = 0.f, tv = 0.f;
        for (int r = 0; r < 64; ++r) {
            float v = fs[FS_IDX(r, d)];
            sv += v;
            tv = fmaf(v, v, tv);
        }
        Ssh[d] = sv;
        float av = sv * sv;
        float dc[4], wv[4];
#pragma unroll
        for (int sl = 0; sl < 4; ++sl) {
            int o = (s0 + sl) * 128 + d;
            dc[sl] = fmaf(CctT[o], tv, CcAT[o] * av);
            wv[sl] = fmaf(CwtT[o], tv, CwAT[o] * av);
        }
#pragma unroll
        for (int m = 1; m < 64; m <<= 1)
#pragma unroll
            for (int sl = 0; sl < 4; ++sl) {
                dc[sl] += __shfl_xor(dc[sl], m);
                wv[sl] += __shfl_xor(wv[sl], m);
            }
        if ((tid & 63) == 0) {
            int w = tid >> 6;
#pragma unroll
            for (int sl = 0; sl < 4; ++sl) {
                parts[w][sl] = dc[sl];
                parts[w][4 + sl] = wv[sl];
            }
        }
    }
    __syncthreads();

    // phase 3: D/U/V for 4 s. thread (ty=tid>>4: rows ty*4+u, tx=tid&15: d0=tx*8)
    int tx = tid & 15, ty = tid >> 4;
    {
        int d0 = tx * 8;
        float4 s0v = *(const float4*)&Ssh[d0];
        float4 s1v = *(const float4*)&Ssh[d0 + 4];
        float sv[8] = {s0v.x, s0v.y, s0v.z, s0v.w, s1v.x, s1v.y, s1v.z, s1v.w};
#pragma unroll
        for (int sl = 0; sl < 4; ++sl) {
            int o = (s0 + sl) * 128 + d0;
            float4 A0, A1;
#define LD8(arr, p) A0 = *(const float4*)&arr[o]; A1 = *(const float4*)&arr[o + 4]; \
            float p[8] = {A0.x, A0.y, A0.z, A0.w, A1.x, A1.y, A1.z, A1.w};
            LD8(CdgT, cg) LD8(CdrT, cr) LD8(CugT, ug) LD8(CurT, ur) LD8(CvgT, vg) LD8(CvrT, vr)
#undef LD8
            float pD[4], pU[4], pV[4];
#pragma unroll
            for (int u = 0; u < 4; ++u) {
                int i = ty * 4 + u;
                float4 fA = *(const float4*)&fs[FS_IDX(i, d0)];
                float4 fB = *(const float4*)&fs[FS_IDX(i, d0 + 4)];
                float fv[8] = {fA.x, fA.y, fA.z, fA.w, fB.x, fB.y, fB.z, fB.w};
                float aD = 0.f, aU = 0.f, aV = 0.f;
#pragma unroll
                for (int e = 0; e < 8; ++e) {
                    float g = fv[e] * fv[e];
                    float rr = fv[e] * sv[e];
                    aD = fmaf(cg[e], g, fmaf(cr[e], rr, aD));
                    aU = fmaf(ug[e], g, fmaf(ur[e], rr, aU));
                    aV = fmaf(vg[e], g, fmaf(vr[e], rr, aV));
                }
                pD[u] = aD; pU[u] = aU; pV[u] = aV;
            }
#pragma unroll
            for (int m = 1; m < 16; m <<= 1)
#pragma unroll
                for (int u = 0; u < 4; ++u) {
                    pD[u] += __shfl_xor(pD[u], m);
                    pU[u] += __shfl_xor(pU[u], m);
                    pV[u] += __shfl_xor(pV[u], m);
                }
            if (tx == 0)
#pragma unroll
                for (int u = 0; u < 4; ++u) {
                    Dv[sl][ty * 4 + u] = pD[u];
                    Uv[sl][ty * 4 + u] = pU[u];
                    Vv[sl][ty * 4 + u] = pV[u];
                }
        }
    }
    __syncthreads();

    // phase 4: Gram for 4 s. rows i=4ty.., cols j=4tx..
    float acc[4][16];
#pragma unroll
    for (int sl = 0; sl < 4; ++sl)
#pragma unroll
        for (int q = 0; q < 16; ++q) acc[sl][q] = 0.f;
    for (int d = 0; d < 128; d += 4) {
        float aif[4][4], bjf[4][4], a4f[4][4];
#pragma unroll
        for (int u = 0; u < 4; ++u) {
            float4 t = *(const float4*)&fs[FS_IDX(ty * 4 + u, d)];
            aif[u][0] = t.x; aif[u][1] = t.y; aif[u][2] = t.z; aif[u][3] = t.w;
        }
#pragma unroll
        for (int v = 0; v < 4; ++v) {
            float4 t = *(const float4*)&fs[FS_IDX(tx * 4 + v, d)];
            bjf[v][0] = t.x; bjf[v][1] = t.y; bjf[v][2] = t.z; bjf[v][3] = t.w;
        }
#pragma unroll
        for (int dd = 0; dd < 4; ++dd) {
            float4 t = *(const float4*)&ash2[(d + dd) * 4];
            a4f[dd][0] = t.x; a4f[dd][1] = t.y; a4f[dd][2] = t.z; a4f[dd][3] = t.w;
        }
#pragma unroll
        for (int dd = 0; dd < 4; ++dd)
#pragma unroll
            for (int sl = 0; sl < 4; ++sl)
#pragma unroll
                for (int u = 0; u < 4; ++u) {
                    float t = aif[u][dd] * a4f[dd][sl];
#pragma unroll
                    for (int v = 0; v < 4; ++v)
                        acc[sl][u * 4 + v] = fmaf(t, bjf[v][dd], acc[sl][u * 4 + v]);
                }
    }

    // phase 5: epilogue + reduce + atomic
    float sDc[4], sW[4];
#pragma unroll
    for (int sl = 0; sl < 4; ++sl) {
        sDc[sl] = parts[0][sl] + parts[1][sl] + diag_bias[s0 + sl];
        sW[sl]  = parts[0][4 + sl] + parts[1][4 + sl] + eq_bias[s0 + sl];
    }
    float psum[4] = {0.f, 0.f, 0.f, 0.f};
#pragma unroll
    for (int u = 0; u < 4; ++u) {
        int i = ty * 4 + u;
#pragma unroll
        for (int v = 0; v < 4; ++v) {
            int j = tx * 4 + v;
#pragma unroll
            for (int sl = 0; sl < 4; ++sl) {
                float val = acc[sl][u * 4 + v] + Uv[sl][i] + Vv[sl][j] + sW[sl];
                if (i == j) val += Dv[sl][i] + sDc[sl];
                psum[sl] += fmaxf(val, 0.0f);
            }
        }
    }
#pragma unroll
    for (int m = 1; m < 64; m <<= 1)
#pragma unroll
        for (int sl = 0; sl < 4; ++sl) psum[sl] += __shfl_xor(psum[sl], m);
    if ((tid & 63) == 0) {
        int w = tid >> 6;
#pragma unroll
        for (int sl = 0; sl < 4; ++sl) red[w][sl] = psum[sl];
    }
    __syncthreads();
    if (tid == 0) {
        float o = 0.f;
#pragma unroll
        for (int sl = 0; sl < 4; ++sl) {
            float tot = red[0][sl] + red[1][sl] + red[2][sl] + red[3][sl];
            o += fmaxf(tot * (1.0f / 4096.0f), 0.0f) * out_w[s0 + sl];
        }
        if (s0 == 0) o += out_b[0];
        atomicAdd(dout + b, o);
    }
}

extern "C" void kernel_launch(void* const* d_in, const int* in_sizes, int n_in,
                              void* d_out, int out_size, void* d_ws, size_t ws_size,
                              hipStream_t stream) {
    const float* x      = (const float*)d_in[0];
    const float* w1     = (const float*)d_in[1];
    const float* b1     = (const float*)d_in[2];
    const float* w2     = (const float*)d_in[3];
    const float* b2     = (const float*)d_in[4];
    const float* fc_w   = (const float*)d_in[5];
    const float* fc_b   = (const float*)d_in[6];
    const float* coeffs = (const float*)d_in[7];
    const float* eqb    = (const float*)d_in[8];
    const float* dgb    = (const float*)d_in[9];
    const float* out_w  = (const float*)d_in[10];
    const float* out_b  = (const float*)d_in[11];

    float* ws = (float*)d_ws;
    float* feat = ws; ws += 131072;    // (1024,128)
    float* fcwT = ws; ws += 131072;    // (1024,128)
    float* w2R  = ws; ws += 51200;     // (64,5,5,32)
    float* CaT  = ws; ws += 16384;
    float* CdgT = ws; ws += 16384;
    float* CdrT = ws; ws += 16384;
    float* CugT = ws; ws += 16384;
    float* CurT = ws; ws += 16384;
    float* CvgT = ws; ws += 16384;
    float* CvrT = ws; ws += 16384;
    float* CctT = ws; ws += 16384;
    float* CcAT = ws; ws += 16384;
    float* CwtT = ws; ws += 16384;
    float* CwAT = ws; ws += 16384;

    k_prep<<<776, 256, 0, stream>>>(coeffs, fc_w, w2,
                                    CaT, CdgT, CdrT, CugT, CurT, CvgT, CvrT,
                                    CctT, CcAT, CwtT, CwAT, fcwT, w2R,
                                    (float*)d_out);
    k_convfc<<<512, 256, 0, stream>>>(x, w1, b1, w2R, b2, fcwT, fc_b, feat);
    k_main2<<<512, 256, 0, stream>>>(feat, CaT, CdgT, CdrT, CugT, CurT,
                                     CvgT, CvrT, CctT, CcAT, CwtT, CwAT,
                                     eqb, dgb, out_w, out_b, (float*)d_out);
}

// Round 6
// 173.386 us; speedup vs baseline: 1.7223x; 1.1909x over previous
//
#include <hip/hip_runtime.h>

// B=16, K=64 -> N=1024 images 28x28; conv1: 1->32ch 12x12; conv2: 32->64ch 4x4
// FLAT=1024, HID=D=128, OUT=S=128, m=64.
//
// out[b,s,i,j] = PP[i,j] + U[i] + V[j] + W + delta_ij*(D[i] + dconst)
// PP = sum_d a[s,d] f_i f_j ; U/V/D from g=f^2, r=f*S ; W,dconst from t=sum f^2, A=S^2

#define FS_IDX(r, d) (((r) << 7) + (((((d) >> 2) ^ (((r) >> 2) & 7))) << 2) + ((d) & 3))

// ---------------------------------------------------------------------------
// K0: one-time prep. Coeff combine -> [s][d] matrices; fc_w transpose ->
// fcwT[k][s]; w2 reshape -> w2R[oc][ky][kx][ic]; zero d_out.
// ---------------------------------------------------------------------------
__global__ __launch_bounds__(256) void k_prep(
        const float* __restrict__ coeffs, const float* __restrict__ fc_w,
        const float* __restrict__ w2,
        float* __restrict__ CaT,  float* __restrict__ CdgT, float* __restrict__ CdrT,
        float* __restrict__ CugT, float* __restrict__ CurT,
        float* __restrict__ CvgT, float* __restrict__ CvrT,
        float* __restrict__ CctT, float* __restrict__ CcAT,
        float* __restrict__ CwtT, float* __restrict__ CwAT,
        float* __restrict__ fcwT, float* __restrict__ w2R,
        float* __restrict__ dout) {
    int idx = blockIdx.x * 256 + threadIdx.x;
    if (idx < 16384) {
        int d = idx >> 7, s = idx & 127;
        const float* c = coeffs + idx * 15;        // coeffs[d][s][p]
        const float im = 1.0f / 64.0f, im2 = 1.0f / 4096.0f;
        int t = s * 128 + d;                       // [s][d] layout
        CaT[t]  = c[9] + c[10];
        CdgT[t] = c[0];
        CdrT[t] = (c[2] + c[3]) * im;
        CurT[t] = (c[5] + c[6]) * im;
        CugT[t] = c[11];
        CvrT[t] = (c[7] + c[8]) * im;
        CvgT[t] = c[12];
        CctT[t] = c[1] * im;
        CcAT[t] = c[4] * im2;
        CwtT[t] = c[13] * im;
        CwAT[t] = c[14] * im2;
        if (idx < 16) dout[idx] = 0.0f;
    } else if (idx < 147456) {
        int e = idx - 16384;                       // e = s*1024 + k
        int s = e >> 10, k = e & 1023;
        fcwT[k * 128 + s] = fc_w[e];
    } else if (idx < 198656) {
        int e = idx - 147456;                      // e = ((oc*5+ky)*5+kx)*32+ic
        int ic = e & 31;
        int q = e >> 5;
        int kx = q % 5, q2 = q / 5, ky = q2 % 5, oc = q2 / 5;
        w2R[e] = w2[oc * 800 + ic * 25 + ky * 5 + kx];
    }
}

// ---------------------------------------------------------------------------
// K1: fused conv1 + conv2 + fc, TWO images per block (512 blocks).
// conv1: thread=(oy,oc), 12-wide row from float4 xs reads; writes transposed
// c1T[pos][ic] with row stride 36 (bank-disjoint icg quads).
// conv2: thread=(oc, icg): 16 outputs over an 8-ic slice; xx-ordered inner
// loop loads each c1T float4 once; ~72 live VGPRs (no spill); 2-shfl reduce.
// fc: thread=(kc,sg): float4 weights x 2 images (8 FMA per 16B load).
// ---------------------------------------------------------------------------
__global__ __launch_bounds__(256) void k_convfc(
        const float* __restrict__ x,  const float* __restrict__ w1,
        const float* __restrict__ b1, const float* __restrict__ w2R,
        const float* __restrict__ b2, const float* __restrict__ fcwT,
        const float* __restrict__ fc_b, float* __restrict__ feat) {
    __shared__ alignas(16) float xs[1568];         // 2 x 784
    __shared__ alignas(16) float w1s[800];
    __shared__ alignas(16) float c1T[144 * 36];    // [pos 144][ic 32 +4 pad]
    __shared__ alignas(16) float ysh[2][1024];
    __shared__ alignas(16) float ps[8][2][128];
    int tid = threadIdx.x;
    int n0 = blockIdx.x * 2;

    {   // stage both images + conv1 weights
        const float4* xsrc = (const float4*)(x + n0 * 784);
        float4* xdst = (float4*)xs;
        for (int i = tid; i < 392; i += 256) xdst[i] = xsrc[i];
        const float4* wsrc = (const float4*)w1;
        float4* wdst = (float4*)w1s;
        for (int i = tid; i < 200; i += 256) wdst[i] = wsrc[i];
    }
    __syncthreads();

    for (int img = 0; img < 2; ++img) {
        // ---- conv1: task = oy*32 + oc ----
        for (int task = tid; task < 384; task += 256) {
            int oy = task >> 5, oc = task & 31;
            const float* wp = w1s + oc * 25;
            float wr[25];
#pragma unroll
            for (int t = 0; t < 25; ++t) wr[t] = wp[t];
            float out[12];
            float bv = b1[oc];
#pragma unroll
            for (int ox = 0; ox < 12; ++ox) out[ox] = bv;
            const float* xb = xs + img * 784 + (oy * 2) * 28;
#pragma unroll
            for (int ky = 0; ky < 5; ++ky) {
                const float4* rp = (const float4*)(xb + ky * 28);
                float4 r0 = rp[0], r1 = rp[1], r2 = rp[2], r3 = rp[3];
                float4 r4 = rp[4], r5 = rp[5], r6 = rp[6];
                float rf[28] = {r0.x, r0.y, r0.z, r0.w, r1.x, r1.y, r1.z, r1.w,
                                r2.x, r2.y, r2.z, r2.w, r3.x, r3.y, r3.z, r3.w,
                                r4.x, r4.y, r4.z, r4.w, r5.x, r5.y, r5.z, r5.w,
                                r6.x, r6.y, r6.z, r6.w};
#pragma unroll
                for (int kx = 0; kx < 5; ++kx) {
                    float wv = wr[ky * 5 + kx];
#pragma unroll
                    for (int ox = 0; ox < 12; ++ox)
                        out[ox] = fmaf(rf[2 * ox + kx], wv, out[ox]);
                }
            }
#pragma unroll
            for (int ox = 0; ox < 12; ++ox)
                c1T[(oy * 12 + ox) * 36 + oc] = fmaxf(out[ox], 0.0f);
        }
        __syncthreads();

        // ---- conv2: tid = oc*4 + icg; 8-ic slice, 16 outputs ----
        {
            int icg = tid & 3, oc = tid >> 2;
            int ic0 = icg * 8;
            float acc[16];
#pragma unroll
            for (int p = 0; p < 16; ++p) acc[p] = 0.0f;
            for (int ky = 0; ky < 5; ++ky) {
                float4 wv[5][2];
#pragma unroll
                for (int kx = 0; kx < 5; ++kx) {
                    const float* wb = &w2R[((oc * 5 + ky) * 5 + kx) * 32 + ic0];
                    wv[kx][0] = *(const float4*)(wb);
                    wv[kx][1] = *(const float4*)(wb + 4);
                }
#pragma unroll
                for (int oyy = 0; oyy < 4; ++oyy) {
                    int y = 2 * oyy + ky;
                    const float* rowb = c1T + (y * 12) * 36 + ic0;
#pragma unroll
                    for (int xx = 0; xx < 12; ++xx) {
                        float4 v0 = *(const float4*)(rowb + xx * 36);
                        float4 v1 = *(const float4*)(rowb + xx * 36 + 4);
#pragma unroll
                        for (int ox = 0; ox < 4; ++ox) {
                            int kx = xx - 2 * ox;
                            if (kx >= 0 && kx < 5) {
                                float4 w0 = wv[kx][0], w1v = wv[kx][1];
                                float s = acc[oyy * 4 + ox];
                                s = fmaf(v0.x, w0.x, s);
                                s = fmaf(v0.y, w0.y, s);
                                s = fmaf(v0.z, w0.z, s);
                                s = fmaf(v0.w, w0.w, s);
                                s = fmaf(v1.x, w1v.x, s);
                                s = fmaf(v1.y, w1v.y, s);
                                s = fmaf(v1.z, w1v.z, s);
                                s = fmaf(v1.w, w1v.w, s);
                                acc[oyy * 4 + ox] = s;
                            }
                        }
                    }
                }
            }
#pragma unroll
            for (int m = 1; m < 4; m <<= 1)
#pragma unroll
                for (int p = 0; p < 16; ++p)
                    acc[p] += __shfl_xor(acc[p], m);
            if (icg == 0) {
                float bb = b2[oc];
#pragma unroll
                for (int p = 0; p < 16; ++p)
                    ysh[img][oc * 16 + p] = fmaxf(acc[p] + bb, 0.0f);
            }
        }
        __syncthreads();
    }

    // ---- fc: tid = kc*32 + sg ----
    {
        int sg = tid & 31, kc = tid >> 5;
        const float* yb0 = &ysh[0][kc * 128];
        const float* yb1 = &ysh[1][kc * 128];
        const float* wb = fcwT + kc * 128 * 128 + sg * 4;
        float4 a0 = {0.f, 0.f, 0.f, 0.f}, a1 = {0.f, 0.f, 0.f, 0.f};
#pragma unroll 4
        for (int i = 0; i < 128; ++i) {
            float4 w = *(const float4*)(wb + i * 128);
            float y0 = yb0[i], y1 = yb1[i];
            a0.x = fmaf(y0, w.x, a0.x); a0.y = fmaf(y0, w.y, a0.y);
            a0.z = fmaf(y0, w.z, a0.z); a0.w = fmaf(y0, w.w, a0.w);
            a1.x = fmaf(y1, w.x, a1.x); a1.y = fmaf(y1, w.y, a1.y);
            a1.z = fmaf(y1, w.z, a1.z); a1.w = fmaf(y1, w.w, a1.w);
        }
        *(float4*)&ps[kc][0][sg * 4] = a0;
        *(float4*)&ps[kc][1][sg * 4] = a1;
    }
    __syncthreads();
    {
        int img = tid >> 7, s = tid & 127;
        float acc = fc_b[s];
#pragma unroll
        for (int kc = 0; kc < 8; ++kc) acc += ps[kc][img][s];
        feat[(n0 + img) * 128 + s] = acc;
    }
}

// ---------------------------------------------------------------------------
// K2: one block per (b, s-quad): 512 blocks, 4 s each. Stages feat[b] once
// (FS_IDX swizzle), computes stats + dconst/W + D/U/V for 4 s, then the
// 64x64x128 Gram with a[s,d] folded in-register. No min-wave bound: the
// phase-4 live set (~124 regs) must NOT be capped at 128 or it spills.
// ---------------------------------------------------------------------------
__global__ __launch_bounds__(256) void k_main2(
        const float* __restrict__ feat,
        const float* __restrict__ CaT,  const float* __restrict__ CdgT,
        const float* __restrict__ CdrT, const float* __restrict__ CugT,
        const float* __restrict__ CurT, const float* __restrict__ CvgT,
        const float* __restrict__ CvrT, const float* __restrict__ CctT,
        const float* __restrict__ CcAT, const float* __restrict__ CwtT,
        const float* __restrict__ CwAT,
        const float* __restrict__ eq_bias, const float* __restrict__ diag_bias,
        const float* __restrict__ out_w,   const float* __restrict__ out_b,
        float* __restrict__ dout) {
    __shared__ alignas(16) float fs[8192];
    __shared__ alignas(16) float ash2[512];        // [d][sl]
    __shared__ alignas(16) float Ssh[128];
    __shared__ float Uv[4][64], Vv[4][64], Dv[4][64];
    __shared__ float parts[2][8];                  // [wave01][dc*4 | w*4]
    __shared__ float red[4][4];                    // [wave][sl]
    int b = blockIdx.x >> 5, sq = blockIdx.x & 31;
    int s0 = sq * 4;
    int tid = threadIdx.x;
    const float* fb = feat + b * 8192;

    // phase 0: stage
    for (int i = tid; i < 8192; i += 256) {
        int r = i >> 7, d = i & 127;
        fs[FS_IDX(r, d)] = fb[i];
    }
    for (int i = tid; i < 512; i += 256) {
        int d = i >> 2, sl = i & 3;
        ash2[d * 4 + sl] = CaT[(s0 + sl) * 128 + d];
    }
    __syncthreads();

    // phase 2: S/T per d + dconst/W partials (threads 0..127)
    if (tid < 128) {
        int d = tid;
        float sv = 0.f, tv = 0.f;
        for (int r = 0; r < 64; ++r) {
            float v = fs[FS_IDX(r, d)];
            sv += v;
            tv = fmaf(v, v, tv);
        }
        Ssh[d] = sv;
        float av = sv * sv;
        float dc[4], wv[4];
#pragma unroll
        for (int sl = 0; sl < 4; ++sl) {
            int o = (s0 + sl) * 128 + d;
            dc[sl] = fmaf(CctT[o], tv, CcAT[o] * av);
            wv[sl] = fmaf(CwtT[o], tv, CwAT[o] * av);
        }
#pragma unroll
        for (int m = 1; m < 64; m <<= 1)
#pragma unroll
            for (int sl = 0; sl < 4; ++sl) {
                dc[sl] += __shfl_xor(dc[sl], m);
                wv[sl] += __shfl_xor(wv[sl], m);
            }
        if ((tid & 63) == 0) {
            int w = tid >> 6;
#pragma unroll
            for (int sl = 0; sl < 4; ++sl) {
                parts[w][sl] = dc[sl];
                parts[w][4 + sl] = wv[sl];
            }
        }
    }
    __syncthreads();

    // phase 3: D/U/V for 4 s. thread (ty=tid>>4: rows ty*4+u, tx=tid&15: d0=tx*8)
    int tx = tid & 15, ty = tid >> 4;
    {
        int d0 = tx * 8;
        float4 s0v = *(const float4*)&Ssh[d0];
        float4 s1v = *(const float4*)&Ssh[d0 + 4];
        float sv[8] = {s0v.x, s0v.y, s0v.z, s0v.w, s1v.x, s1v.y, s1v.z, s1v.w};
#pragma unroll
        for (int sl = 0; sl < 4; ++sl) {
            int o = (s0 + sl) * 128 + d0;
            float4 A0, A1;
#define LD8(arr, p) A0 = *(const float4*)&arr[o]; A1 = *(const float4*)&arr[o + 4]; \
            float p[8] = {A0.x, A0.y, A0.z, A0.w, A1.x, A1.y, A1.z, A1.w};
            LD8(CdgT, cg) LD8(CdrT, cr) LD8(CugT, ug) LD8(CurT, ur) LD8(CvgT, vg) LD8(CvrT, vr)
#undef LD8
            float pD[4], pU[4], pV[4];
#pragma unroll
            for (int u = 0; u < 4; ++u) {
                int i = ty * 4 + u;
                float4 fA = *(const float4*)&fs[FS_IDX(i, d0)];
                float4 fB = *(const float4*)&fs[FS_IDX(i, d0 + 4)];
                float fv[8] = {fA.x, fA.y, fA.z, fA.w, fB.x, fB.y, fB.z, fB.w};
                float aD = 0.f, aU = 0.f, aV = 0.f;
#pragma unroll
                for (int e = 0; e < 8; ++e) {
                    float g = fv[e] * fv[e];
                    float rr = fv[e] * sv[e];
                    aD = fmaf(cg[e], g, fmaf(cr[e], rr, aD));
                    aU = fmaf(ug[e], g, fmaf(ur[e], rr, aU));
                    aV = fmaf(vg[e], g, fmaf(vr[e], rr, aV));
                }
                pD[u] = aD; pU[u] = aU; pV[u] = aV;
            }
#pragma unroll
            for (int m = 1; m < 16; m <<= 1)
#pragma unroll
                for (int u = 0; u < 4; ++u) {
                    pD[u] += __shfl_xor(pD[u], m);
                    pU[u] += __shfl_xor(pU[u], m);
                    pV[u] += __shfl_xor(pV[u], m);
                }
            if (tx == 0)
#pragma unroll
                for (int u = 0; u < 4; ++u) {
                    Dv[sl][ty * 4 + u] = pD[u];
                    Uv[sl][ty * 4 + u] = pU[u];
                    Vv[sl][ty * 4 + u] = pV[u];
                }
        }
    }
    __syncthreads();

    // phase 4: Gram for 4 s. rows i=4ty.., cols j=4tx..
    float acc[4][16];
#pragma unroll
    for (int sl = 0; sl < 4; ++sl)
#pragma unroll
        for (int q = 0; q < 16; ++q) acc[sl][q] = 0.f;
    for (int d = 0; d < 128; d += 4) {
        float aif[4][4], bjf[4][4], a4f[4][4];
#pragma unroll
        for (int u = 0; u < 4; ++u) {
            float4 t = *(const float4*)&fs[FS_IDX(ty * 4 + u, d)];
            aif[u][0] = t.x; aif[u][1] = t.y; aif[u][2] = t.z; aif[u][3] = t.w;
        }
#pragma unroll
        for (int v = 0; v < 4; ++v) {
            float4 t = *(const float4*)&fs[FS_IDX(tx * 4 + v, d)];
            bjf[v][0] = t.x; bjf[v][1] = t.y; bjf[v][2] = t.z; bjf[v][3] = t.w;
        }
#pragma unroll
        for (int dd = 0; dd < 4; ++dd) {
            float4 t = *(const float4*)&ash2[(d + dd) * 4];
            a4f[dd][0] = t.x; a4f[dd][1] = t.y; a4f[dd][2] = t.z; a4f[dd][3] = t.w;
        }
#pragma unroll
        for (int dd = 0; dd < 4; ++dd)
#pragma unroll
            for (int sl = 0; sl < 4; ++sl)
#pragma unroll
                for (int u = 0; u < 4; ++u) {
                    float t = aif[u][dd] * a4f[dd][sl];
#pragma unroll
                    for (int v = 0; v < 4; ++v)
                        acc[sl][u * 4 + v] = fmaf(t, bjf[v][dd], acc[sl][u * 4 + v]);
                }
    }

    // phase 5: epilogue + reduce + atomic
    float sDc[4], sW[4];
#pragma unroll
    for (int sl = 0; sl < 4; ++sl) {
        sDc[sl] = parts[0][sl] + parts[1][sl] + diag_bias[s0 + sl];
        sW[sl]  = parts[0][4 + sl] + parts[1][4 + sl] + eq_bias[s0 + sl];
    }
    float psum[4] = {0.f, 0.f, 0.f, 0.f};
#pragma unroll
    for (int u = 0; u < 4; ++u) {
        int i = ty * 4 + u;
#pragma unroll
        for (int v = 0; v < 4; ++v) {
            int j = tx * 4 + v;
#pragma unroll
            for (int sl = 0; sl < 4; ++sl) {
                float val = acc[sl][u * 4 + v] + Uv[sl][i] + Vv[sl][j] + sW[sl];
                if (i == j) val += Dv[sl][i] + sDc[sl];
                psum[sl] += fmaxf(val, 0.0f);
            }
        }
    }
#pragma unroll
    for (int m = 1; m < 64; m <<= 1)
#pragma unroll
        for (int sl = 0; sl < 4; ++sl) psum[sl] += __shfl_xor(psum[sl], m);
    if ((tid & 63) == 0) {
        int w = tid >> 6;
#pragma unroll
        for (int sl = 0; sl < 4; ++sl) red[w][sl] = psum[sl];
    }
    __syncthreads();
    if (tid == 0) {
        float o = 0.f;
#pragma unroll
        for (int sl = 0; sl < 4; ++sl) {
            float tot = red[0][sl] + red[1][sl] + red[2][sl] + red[3][sl];
            o += fmaxf(tot * (1.0f / 4096.0f), 0.0f) * out_w[s0 + sl];
        }
        if (s0 == 0) o += out_b[0];
        atomicAdd(dout + b, o);
    }
}

extern "C" void kernel_launch(void* const* d_in, const int* in_sizes, int n_in,
                              void* d_out, int out_size, void* d_ws, size_t ws_size,
                              hipStream_t stream) {
    const float* x      = (const float*)d_in[0];
    const float* w1     = (const float*)d_in[1];
    const float* b1     = (const float*)d_in[2];
    const float* w2     = (const float*)d_in[3];
    const float* b2     = (const float*)d_in[4];
    const float* fc_w   = (const float*)d_in[5];
    const float* fc_b   = (const float*)d_in[6];
    const float* coeffs = (const float*)d_in[7];
    const float* eqb    = (const float*)d_in[8];
    const float* dgb    = (const float*)d_in[9];
    const float* out_w  = (const float*)d_in[10];
    const float* out_b  = (const float*)d_in[11];

    float* ws = (float*)d_ws;
    float* feat = ws; ws += 131072;    // (1024,128)
    float* fcwT = ws; ws += 131072;    // (1024,128)
    float* w2R  = ws; ws += 51200;     // (64,5,5,32)
    float* CaT  = ws; ws += 16384;
    float* CdgT = ws; ws += 16384;
    float* CdrT = ws; ws += 16384;
    float* CugT = ws; ws += 16384;
    float* CurT = ws; ws += 16384;
    float* CvgT = ws; ws += 16384;
    float* CvrT = ws; ws += 16384;
    float* CctT = ws; ws += 16384;
    float* CcAT = ws; ws += 16384;
    float* CwtT = ws; ws += 16384;
    float* CwAT = ws; ws += 16384;

    k_prep<<<776, 256, 0, stream>>>(coeffs, fc_w, w2,
                                    CaT, CdgT, CdrT, CugT, CurT, CvgT, CvrT,
                                    CctT, CcAT, CwtT, CwAT, fcwT, w2R,
                                    (float*)d_out);
    k_convfc<<<512, 256, 0, stream>>>(x, w1, b1, w2R, b2, fcwT, fc_b, feat);
    k_main2<<<512, 256, 0, stream>>>(feat, CaT, CdgT, CdrT, CugT, CurT,
                                     CvgT, CvrT, CctT, CcAT, CwtT, CwAT,
                                     eqb, dgb, out_w, out_b, (float*)d_out);
}